// Round 1
// baseline (11265.533 us; speedup 1.0000x reference)
//
#include <hip/hip_runtime.h>
#include <math.h>

#define H 64
#define F 18

// ---------------------------------------------------------------- embed ----
__global__ __launch_bounds__(256) void embed_kernel(
    const float* __restrict__ nf, const float* __restrict__ W,
    const float* __restrict__ b, float* __restrict__ x, int N)
{
    int n = blockIdx.x * 256 + threadIdx.x;
    if (n >= N) return;
    float acc[H];
#pragma unroll
    for (int j = 0; j < H; ++j) acc[j] = b[j];
    const float* f = nf + (long)n * F;
#pragma unroll
    for (int i = 0; i < F; ++i) {
        float c = f[i];
        const float* w = W + i * H;
#pragma unroll
        for (int j = 0; j < H; ++j) acc[j] += c * w[j];
    }
    float* xo = x + (long)n * H;
#pragma unroll
    for (int j = 0; j < H; ++j) xo[j] = fmaxf(acc[j], 0.f);
}

// ----------------------------------------------------------------- edge ----
// lane = edge. Weights are wave-uniform -> s_load (SGPR) operands.
// msg: cat[128] @ W1[128,64] -> relu -> @ W2[64,64]
// att: cat[128] @ aW1[128,32] -> relu -> @ aW2[32] -> sigmoid
__global__ __launch_bounds__(256) void edge_kernel(
    const float* __restrict__ x,
    const int* __restrict__ row, const int* __restrict__ col,
    const float* __restrict__ ew,
    const float* __restrict__ W1, const float* __restrict__ b1,
    const float* __restrict__ W2, const float* __restrict__ b2,
    const float* __restrict__ aW1, const float* __restrict__ ab1,
    const float* __restrict__ aW2, const float* __restrict__ ab2,
    float* __restrict__ agg, float* __restrict__ nrm, int E)
{
    int e = blockIdx.x * 256 + threadIdx.x;
    bool valid = e < E;
    int ei = valid ? e : 0;
    int r = row[ei];
    int c = col[ei];
    float w_edge = ew[ei];

    const float4* xr4 = (const float4*)(x + (long)r * H);
    const float4* xc4 = (const float4*)(x + (long)c * H);

    float accm[H];
    float acca[H / 2];
#pragma unroll
    for (int j = 0; j < H; ++j) accm[j] = 0.f;
#pragma unroll
    for (int j = 0; j < H / 2; ++j) acca[j] = 0.f;

#pragma unroll
    for (int half = 0; half < 2; ++half) {
        const float4* src = half ? xc4 : xr4;
        const float* W1h = W1 + half * H * H;           // rows [64..127] for half=1
        const float* aW1h = aW1 + half * H * (H / 2);
        for (int i4 = 0; i4 < H / 4; ++i4) {
            float4 v = src[i4];
#pragma unroll
            for (int s = 0; s < 4; ++s) {
                float cs = (s == 0) ? v.x : (s == 1) ? v.y : (s == 2) ? v.z : v.w;
                const float* w = W1h + (i4 * 4 + s) * H;
                const float* aw = aW1h + (i4 * 4 + s) * (H / 2);
#pragma unroll
                for (int j = 0; j < H; ++j) accm[j] += cs * w[j];
#pragma unroll
                for (int j = 0; j < H / 2; ++j) acca[j] += cs * aw[j];
            }
        }
    }

    // attention head -> scalar
    float za = ab2[0];
#pragma unroll
    for (int k = 0; k < H / 2; ++k)
        za += fmaxf(acca[k] + ab1[k], 0.f) * aW2[k];
    float att = 1.f / (1.f + __expf(-za));
    float fw = w_edge * att;

    // msg layer 2
    float h[H];
#pragma unroll
    for (int k = 0; k < H; ++k) h[k] = fmaxf(accm[k] + b1[k], 0.f);
    float acc2[H];
#pragma unroll
    for (int j = 0; j < H; ++j) acc2[j] = b2[j];
#pragma unroll
    for (int k = 0; k < H; ++k) {
        float hk = h[k];
        const float* w = W2 + k * H;
#pragma unroll
        for (int j = 0; j < H; ++j) acc2[j] += hk * w[j];
    }

    if (valid) {
        float* dst = agg + (long)c * H;
#pragma unroll
        for (int j = 0; j < H; ++j) atomicAdd(dst + j, acc2[j] * fw);
        atomicAdd(nrm + c, fw);
    }
}

// --------------------------------------------------------------- update ----
__global__ __launch_bounds__(256) void update_kernel(
    float* __restrict__ x, const float* __restrict__ agg,
    const float* __restrict__ nrm,
    const float* __restrict__ W1, const float* __restrict__ b1,
    const float* __restrict__ W2, const float* __restrict__ b2, int N)
{
    int n = blockIdx.x * 256 + threadIdx.x;
    if (n >= N) return;
    float inv = 1.f / fmaxf(nrm[n], 1e-6f);

    float accu[H];
#pragma unroll
    for (int j = 0; j < H; ++j) accu[j] = 0.f;

    const float4* xa = (const float4*)(x + (long)n * H);
    const float4* ga = (const float4*)(agg + (long)n * H);

    for (int i4 = 0; i4 < H / 4; ++i4) {
        float4 v = xa[i4];
#pragma unroll
        for (int s = 0; s < 4; ++s) {
            float cs = (s == 0) ? v.x : (s == 1) ? v.y : (s == 2) ? v.z : v.w;
            const float* w = W1 + (i4 * 4 + s) * H;
#pragma unroll
            for (int j = 0; j < H; ++j) accu[j] += cs * w[j];
        }
    }
    for (int i4 = 0; i4 < H / 4; ++i4) {
        float4 v = ga[i4];
        v.x *= inv; v.y *= inv; v.z *= inv; v.w *= inv;
#pragma unroll
        for (int s = 0; s < 4; ++s) {
            float cs = (s == 0) ? v.x : (s == 1) ? v.y : (s == 2) ? v.z : v.w;
            const float* w = W1 + (H + i4 * 4 + s) * H;
#pragma unroll
            for (int j = 0; j < H; ++j) accu[j] += cs * w[j];
        }
    }

    float h[H];
#pragma unroll
    for (int k = 0; k < H; ++k) h[k] = fmaxf(accu[k] + b1[k], 0.f);
    float acc2[H];
#pragma unroll
    for (int j = 0; j < H; ++j) acc2[j] = b2[j];
#pragma unroll
    for (int k = 0; k < H; ++k) {
        float hk = h[k];
        const float* w = W2 + k * H;
#pragma unroll
        for (int j = 0; j < H; ++j) acc2[j] += hk * w[j];
    }

    float* xo = x + (long)n * H;
#pragma unroll
    for (int j = 0; j < H; ++j) xo[j] = fmaxf(acc2[j] + xo[j], 0.f);
}

// ----------------------------------------------------------------- head ----
__global__ __launch_bounds__(256) void max_kernel(
    const float* __restrict__ x, unsigned int* __restrict__ serp, int N)
{
    int j = threadIdx.x & (H - 1);
    int g = (blockIdx.x * 256 + threadIdx.x) >> 6;
    int stride = (gridDim.x * 256) >> 6;
    float m = 0.f;  // x >= 0 after relu
    for (int n = g; n < N; n += stride) m = fmaxf(m, x[(long)n * H + j]);
    atomicMax(serp + j, __float_as_uint(m));  // valid order for floats >= 0
}

__global__ void head_kernel(const unsigned int* __restrict__ serp,
                            const float* __restrict__ hW,
                            const float* __restrict__ hb,
                            float* __restrict__ out)
{
    int j = threadIdx.x;  // 64 threads = 1 wave
    float v = __uint_as_float(serp[j]) * hW[j];
#pragma unroll
    for (int off = 32; off > 0; off >>= 1) v += __shfl_down(v, off);
    if (j == 0) out[0] = v + hb[0];
}

// --------------------------------------------------------------- launch ----
extern "C" void kernel_launch(void* const* d_in, const int* in_sizes, int n_in,
                              void* d_out, int out_size, void* d_ws, size_t ws_size,
                              hipStream_t stream)
{
    const float* nf  = (const float*)d_in[0];
    const int*   ei  = (const int*)d_in[1];
    const float* ew  = (const float*)d_in[2];
    const float* eW  = (const float*)d_in[3];
    const float* eb  = (const float*)d_in[4];
    const float* mW1 = (const float*)d_in[5];
    const float* mb1 = (const float*)d_in[6];
    const float* mW2 = (const float*)d_in[7];
    const float* mb2 = (const float*)d_in[8];
    const float* aW1 = (const float*)d_in[9];
    const float* ab1 = (const float*)d_in[10];
    const float* aW2 = (const float*)d_in[11];
    const float* ab2 = (const float*)d_in[12];
    const float* uW1 = (const float*)d_in[13];
    const float* ub1 = (const float*)d_in[14];
    const float* uW2 = (const float*)d_in[15];
    const float* ub2 = (const float*)d_in[16];
    const float* hW  = (const float*)d_in[17];
    const float* hb  = (const float*)d_in[18];

    int N = in_sizes[0] / F;
    int E = in_sizes[2];
    const int* row = ei;
    const int* col = ei + E;

    float* x   = (float*)d_ws;                 // N*H
    float* agg = x + (size_t)N * H;            // N*H
    float* nrm = agg + (size_t)N * H;          // N
    unsigned int* serp = (unsigned int*)(nrm + N);  // H

    int nb_n = (N + 255) / 256;
    int nb_e = (E + 255) / 256;

    embed_kernel<<<nb_n, 256, 0, stream>>>(nf, eW, eb, x, N);

    for (int l = 0; l < 2; ++l) {
        hipMemsetAsync(agg, 0, ((size_t)N * H + N) * sizeof(float), stream);
        edge_kernel<<<nb_e, 256, 0, stream>>>(
            x, row, col, ew,
            mW1 + (size_t)l * 2 * H * H, mb1 + (size_t)l * H,
            mW2 + (size_t)l * H * H,     mb2 + (size_t)l * H,
            aW1 + (size_t)l * 2 * H * (H / 2), ab1 + (size_t)l * (H / 2),
            aW2 + (size_t)l * (H / 2),   ab2 + (size_t)l,
            agg, nrm, E);
        update_kernel<<<nb_n, 256, 0, stream>>>(
            x, agg, nrm,
            uW1 + (size_t)l * 2 * H * H, ub1 + (size_t)l * H,
            uW2 + (size_t)l * H * H,     ub2 + (size_t)l * H, N);
    }

    hipMemsetAsync(serp, 0, H * sizeof(unsigned int), stream);
    max_kernel<<<256, 256, 0, stream>>>(x, serp, N);
    head_kernel<<<1, 64, 0, stream>>>(serp, hW, hb, (float*)d_out);
}

// Round 2
// 2559.433 us; speedup vs baseline: 4.4016x; 4.4016x over previous
//
#include <hip/hip_runtime.h>
#include <math.h>

#define H 64
#define F 18

// ---------------------------------------------------------------- embed ----
__global__ __launch_bounds__(256) void embed_kernel(
    const float* __restrict__ nf, const float* __restrict__ W,
    const float* __restrict__ b, float* __restrict__ x, int N)
{
    int n = blockIdx.x * 256 + threadIdx.x;
    if (n >= N) return;
    float acc[H];
#pragma unroll
    for (int j = 0; j < H; ++j) acc[j] = b[j];
    const float* f = nf + (long)n * F;
#pragma unroll
    for (int i = 0; i < F; ++i) {
        float c = f[i];
        const float* w = W + i * H;
#pragma unroll
        for (int j = 0; j < H; ++j) acc[j] += c * w[j];
    }
    float* xo = x + (long)n * H;
#pragma unroll
    for (int j = 0; j < H; ++j) xo[j] = fmaxf(acc[j], 0.f);
}

// ------------------------------------------------------- linked lists -----
// Per-chunk, per-destination-node linked list of edges (atomic-free gather
// later). head[c*N + n] = most recent edge in chunk c with col==n; next[e]
// chains. Order irrelevant for sums.
__global__ __launch_bounds__(256) void build_ll_kernel(
    const int* __restrict__ col, int* __restrict__ head,
    int* __restrict__ next, int N, int E, int chunkE)
{
    int e = blockIdx.x * 256 + threadIdx.x;
    if (e >= E) return;
    int c = e / chunkE;
    next[e] = atomicExch(head + (size_t)c * N + col[e], e);
}

// ----------------------------------------------------------------- edge ----
// lane = edge; weights wave-uniform (SGPR). Computes att (sigmoid head) and
// h = relu(cat@W1+b1); writes h*fw. msg-W2 is applied post-aggregation
// (linearity). Two phases to cap live VGPRs (32-acc phase, then 64-acc).
__global__ __launch_bounds__(256) void edge_kernel(
    const float* __restrict__ x,
    const int* __restrict__ row, const int* __restrict__ col,
    const float* __restrict__ ew,
    const float* __restrict__ W1, const float* __restrict__ b1,
    const float* __restrict__ aW1, const float* __restrict__ ab1,
    const float* __restrict__ aW2, const float* __restrict__ ab2,
    float* __restrict__ hfw, float* __restrict__ fwbuf,
    int e0, int e1)
{
    int e = e0 + blockIdx.x * 256 + threadIdx.x;
    if (e >= e1) return;
    const float4* xr = (const float4*)(x + (size_t)row[e] * H);
    const float4* xc = (const float4*)(x + (size_t)col[e] * H);

    float fw;
    {
        float acca[H / 2];
#pragma unroll
        for (int j = 0; j < H / 2; ++j) acca[j] = 0.f;
#pragma unroll
        for (int half = 0; half < 2; ++half) {
            const float4* src = half ? xc : xr;
            const float* aW = aW1 + half * H * (H / 2);
            for (int i4 = 0; i4 < H / 4; ++i4) {
                float4 v = src[i4];
#pragma unroll
                for (int s = 0; s < 4; ++s) {
                    float cs = (s == 0) ? v.x : (s == 1) ? v.y : (s == 2) ? v.z : v.w;
                    const float* w = aW + (i4 * 4 + s) * (H / 2);
#pragma unroll
                    for (int j = 0; j < H / 2; ++j) acca[j] += cs * w[j];
                }
            }
        }
        float za = ab2[0];
#pragma unroll
        for (int k = 0; k < H / 2; ++k)
            za += fmaxf(acca[k] + ab1[k], 0.f) * aW2[k];
        fw = ew[e] / (1.f + __expf(-za));
    }

    float accm[H];
#pragma unroll
    for (int j = 0; j < H; ++j) accm[j] = 0.f;
#pragma unroll
    for (int half = 0; half < 2; ++half) {
        const float4* src = half ? xc : xr;
        const float* Wh = W1 + half * H * H;
        for (int i4 = 0; i4 < H / 4; ++i4) {
            float4 v = src[i4];
#pragma unroll
            for (int s = 0; s < 4; ++s) {
                float cs = (s == 0) ? v.x : (s == 1) ? v.y : (s == 2) ? v.z : v.w;
                const float* w = Wh + (i4 * 4 + s) * H;
#pragma unroll
                for (int j = 0; j < H; ++j) accm[j] += cs * w[j];
            }
        }
    }

    int le = e - e0;
    float4* out = (float4*)(hfw + (size_t)le * H);
#pragma unroll
    for (int j4 = 0; j4 < H / 4; ++j4) {
        float4 o;
        o.x = fmaxf(accm[4 * j4 + 0] + b1[4 * j4 + 0], 0.f) * fw;
        o.y = fmaxf(accm[4 * j4 + 1] + b1[4 * j4 + 1], 0.f) * fw;
        o.z = fmaxf(accm[4 * j4 + 2] + b1[4 * j4 + 2], 0.f) * fw;
        o.w = fmaxf(accm[4 * j4 + 3] + b1[4 * j4 + 3], 0.f) * fw;
        out[j4] = o;
    }
    fwbuf[le] = fw;
}

// --------------------------------------------------------------- gather ----
// wave per node, lane per feature. e is wave-uniform (all lanes load the same
// next[e] -> L1 broadcast); hfw row reads are coalesced 256B. No atomics.
__global__ __launch_bounds__(256) void gather_kernel(
    const float* __restrict__ hfw, const float* __restrict__ fwbuf,
    const int* __restrict__ head, const int* __restrict__ next,
    float* __restrict__ agg, float* __restrict__ fwsum, int N, int e0)
{
    int wid = (blockIdx.x * 256 + threadIdx.x) >> 6;
    int lane = threadIdx.x & 63;
    if (wid >= N) return;
    int e = head[wid];
    float acc = 0.f, fws = 0.f;
    while (e >= 0) {
        int le = e - e0;
        acc += hfw[(size_t)le * H + lane];
        fws += fwbuf[le];
        e = next[e];
    }
    agg[(size_t)wid * H + lane] += acc;
    if (lane == 0) fwsum[wid] += fws;
}

// --------------------------------------------------------------- update ----
// thread per node: aggregated = (agg@mW2 + fwsum*mb2)/clip(fwsum), then the
// update MLP + residual relu.
__global__ __launch_bounds__(256) void update_kernel(
    float* __restrict__ x, const float* __restrict__ agg,
    const float* __restrict__ fwsum,
    const float* __restrict__ mW2, const float* __restrict__ mb2,
    const float* __restrict__ W1, const float* __restrict__ b1,
    const float* __restrict__ W2, const float* __restrict__ b2, int N)
{
    int n = blockIdx.x * 256 + threadIdx.x;
    if (n >= N) return;
    float fws = fwsum[n];
    float inv = 1.f / fmaxf(fws, 1e-6f);

    // aggregated (after msg-W2 + norm)
    float aggv[H];
#pragma unroll
    for (int j = 0; j < H; ++j) aggv[j] = fws * mb2[j];
    const float4* ga = (const float4*)(agg + (size_t)n * H);
    for (int i4 = 0; i4 < H / 4; ++i4) {
        float4 v = ga[i4];
#pragma unroll
        for (int s = 0; s < 4; ++s) {
            float cs = (s == 0) ? v.x : (s == 1) ? v.y : (s == 2) ? v.z : v.w;
            const float* w = mW2 + (i4 * 4 + s) * H;
#pragma unroll
            for (int j = 0; j < H; ++j) aggv[j] += cs * w[j];
        }
    }
#pragma unroll
    for (int j = 0; j < H; ++j) aggv[j] *= inv;

    // update MLP layer 1: cat = [x[n], aggregated]
    float accu[H];
#pragma unroll
    for (int j = 0; j < H; ++j) accu[j] = 0.f;
    const float4* xa = (const float4*)(x + (size_t)n * H);
    for (int i4 = 0; i4 < H / 4; ++i4) {
        float4 v = xa[i4];
#pragma unroll
        for (int s = 0; s < 4; ++s) {
            float cs = (s == 0) ? v.x : (s == 1) ? v.y : (s == 2) ? v.z : v.w;
            const float* w = W1 + (i4 * 4 + s) * H;
#pragma unroll
            for (int j = 0; j < H; ++j) accu[j] += cs * w[j];
        }
    }
#pragma unroll
    for (int k = 0; k < H; ++k) {
        float cs = aggv[k];
        const float* w = W1 + (H + k) * H;
#pragma unroll
        for (int j = 0; j < H; ++j) accu[j] += cs * w[j];
    }

    float h[H];
#pragma unroll
    for (int k = 0; k < H; ++k) h[k] = fmaxf(accu[k] + b1[k], 0.f);
    float acc2[H];
#pragma unroll
    for (int j = 0; j < H; ++j) acc2[j] = b2[j];
#pragma unroll
    for (int k = 0; k < H; ++k) {
        float hk = h[k];
        const float* w = W2 + k * H;
#pragma unroll
        for (int j = 0; j < H; ++j) acc2[j] += hk * w[j];
    }

    float* xo = x + (size_t)n * H;
#pragma unroll
    for (int j = 0; j < H; ++j) xo[j] = fmaxf(acc2[j] + xo[j], 0.f);
}

// ----------------------------------------------------------------- head ----
__global__ __launch_bounds__(256) void max_kernel(
    const float* __restrict__ x, unsigned int* __restrict__ serp, int N)
{
    int j = threadIdx.x & (H - 1);
    int g = (blockIdx.x * 256 + threadIdx.x) >> 6;
    int stride = (gridDim.x * 256) >> 6;
    float m = 0.f;  // x >= 0 after relu
    for (int n = g; n < N; n += stride) m = fmaxf(m, x[(size_t)n * H + j]);
    atomicMax(serp + j, __float_as_uint(m));  // valid for floats >= 0
}

__global__ void head_kernel(const unsigned int* __restrict__ serp,
                            const float* __restrict__ hW,
                            const float* __restrict__ hb,
                            float* __restrict__ out)
{
    int j = threadIdx.x;  // 64 threads = 1 wave
    float v = __uint_as_float(serp[j]) * hW[j];
#pragma unroll
    for (int off = 32; off > 0; off >>= 1) v += __shfl_down(v, off);
    if (j == 0) out[0] = v + hb[0];
}

// --------------------------------------------------------------- launch ----
extern "C" void kernel_launch(void* const* d_in, const int* in_sizes, int n_in,
                              void* d_out, int out_size, void* d_ws, size_t ws_size,
                              hipStream_t stream)
{
    const float* nf  = (const float*)d_in[0];
    const int*   ei  = (const int*)d_in[1];
    const float* ew  = (const float*)d_in[2];
    const float* eW  = (const float*)d_in[3];
    const float* eb  = (const float*)d_in[4];
    const float* mW1 = (const float*)d_in[5];
    const float* mb1 = (const float*)d_in[6];
    const float* mW2 = (const float*)d_in[7];
    const float* mb2 = (const float*)d_in[8];
    const float* aW1 = (const float*)d_in[9];
    const float* ab1 = (const float*)d_in[10];
    const float* aW2 = (const float*)d_in[11];
    const float* ab2 = (const float*)d_in[12];
    const float* uW1 = (const float*)d_in[13];
    const float* ub1 = (const float*)d_in[14];
    const float* uW2 = (const float*)d_in[15];
    const float* ub2 = (const float*)d_in[16];
    const float* hW  = (const float*)d_in[17];
    const float* hb  = (const float*)d_in[18];

    int N = in_sizes[0] / F;
    int E = in_sizes[2];
    const int* row = ei;
    const int* col = ei + E;

    // ---- workspace layout (float/int units; everything stays 16B aligned:
    // N, E, N*H, chunkE4 are all multiples of 4) ----
    const int kcand[6] = {1, 2, 4, 8, 16, 32};
    int k = 32, chunkE4 = 0;
    for (int i = 0; i < 6; ++i) {
        int kk = kcand[i];
        int ce = ((E + kk - 1) / kk + 3) & ~3;
        size_t elems = (size_t)2 * N * H + N + H + E + (size_t)kk * N
                     + (size_t)ce + (size_t)ce * H;
        if (elems * 4 <= ws_size) { k = kk; chunkE4 = ce; break; }
        if (i == 5) chunkE4 = ce;  // last resort
    }
    int chunkE = (E + k - 1) / k;

    float* x    = (float*)d_ws;                       // N*H
    float* agg  = x + (size_t)N * H;                  // N*H
    float* fws  = agg + (size_t)N * H;                // N   (contiguous w/ agg)
    unsigned int* serp = (unsigned int*)(fws + N);    // H
    int*   next = (int*)(serp + H);                   // E
    int*   head = next + E;                           // k*N
    float* fwbuf = (float*)(head + (size_t)k * N);    // chunkE4
    float* hfw  = fwbuf + chunkE4;                    // chunkE4*H

    int nb_n = (N + 255) / 256;
    int nb_e = (E + 255) / 256;

    hipMemsetAsync(head, 0xFF, (size_t)k * N * sizeof(int), stream);
    build_ll_kernel<<<nb_e, 256, 0, stream>>>(col, head, next, N, E, chunkE);
    embed_kernel<<<nb_n, 256, 0, stream>>>(nf, eW, eb, x, N);

    for (int l = 0; l < 2; ++l) {
        hipMemsetAsync(agg, 0, ((size_t)N * H + N) * sizeof(float), stream);
        for (int c = 0; c < k; ++c) {
            int e0 = c * chunkE;
            int e1 = (e0 + chunkE < E) ? e0 + chunkE : E;
            int nb_c = (e1 - e0 + 255) / 256;
            edge_kernel<<<nb_c, 256, 0, stream>>>(
                x, row, col, ew,
                mW1 + (size_t)l * 2 * H * H, mb1 + (size_t)l * H,
                aW1 + (size_t)l * 2 * H * (H / 2), ab1 + (size_t)l * (H / 2),
                aW2 + (size_t)l * (H / 2),   ab2 + (size_t)l,
                hfw, fwbuf, e0, e1);
            gather_kernel<<<(N + 3) / 4, 256, 0, stream>>>(
                hfw, fwbuf, head + (size_t)c * N, next, agg, fws, N, e0);
        }
        update_kernel<<<nb_n, 256, 0, stream>>>(
            x, agg, fws,
            mW2 + (size_t)l * H * H,     mb2 + (size_t)l * H,
            uW1 + (size_t)l * 2 * H * H, ub1 + (size_t)l * H,
            uW2 + (size_t)l * H * H,     ub2 + (size_t)l * H, N);
    }

    hipMemsetAsync(serp, 0, H * sizeof(unsigned int), stream);
    max_kernel<<<256, 256, 0, stream>>>(x, serp, N);
    head_kernel<<<1, 64, 0, stream>>>(serp, hW, hb, (float*)d_out);
}

// Round 4
// 2095.955 us; speedup vs baseline: 5.3749x; 1.2211x over previous
//
#include <hip/hip_runtime.h>
#include <hip/hip_bf16.h>
#include <math.h>

#define H 64
#define F 18

// ---------------------------------------------------------------- embed ----
__global__ __launch_bounds__(256) void embed_kernel(
    const float* __restrict__ nf, const float* __restrict__ W,
    const float* __restrict__ b, float* __restrict__ x, int N)
{
    int n = blockIdx.x * 256 + threadIdx.x;
    if (n >= N) return;
    float acc[H];
#pragma unroll
    for (int j = 0; j < H; ++j) acc[j] = b[j];
    const float* f = nf + (long)n * F;
#pragma unroll
    for (int i = 0; i < F; ++i) {
        float c = f[i];
        const float* w = W + i * H;
#pragma unroll
        for (int j = 0; j < H; ++j) acc[j] += c * w[j];
    }
    float* xo = x + (long)n * H;
#pragma unroll
    for (int j = 0; j < H; ++j) xo[j] = fmaxf(acc[j], 0.f);
}

// ----------------------------------------------- counting sort by col -----
__global__ __launch_bounds__(256) void hist_kernel(
    const int* __restrict__ col, int* __restrict__ deg, int E)
{
    int e = blockIdx.x * 256 + threadIdx.x;
    if (e < E) atomicAdd(deg + col[e], 1);
}

// 3-phase exclusive scan over deg[N] -> startp[N]; 1024 elems/block.
__global__ __launch_bounds__(256) void scan1_kernel(
    const int* __restrict__ deg, int* __restrict__ part,
    int* __restrict__ bsum, int N)
{
    __shared__ int lds[256];
    int t = threadIdx.x;
    int base = blockIdx.x * 1024 + t * 4;
    int v[4];
#pragma unroll
    for (int s = 0; s < 4; ++s) v[s] = (base + s < N) ? deg[base + s] : 0;
    int sum = v[0] + v[1] + v[2] + v[3];
    lds[t] = sum;
    __syncthreads();
    for (int off = 1; off < 256; off <<= 1) {
        int xv = (t >= off) ? lds[t - off] : 0;
        __syncthreads();
        lds[t] += xv;
        __syncthreads();
    }
    int excl = lds[t] - sum;
    if (t == 255) bsum[blockIdx.x] = lds[255];
    int p = excl;
#pragma unroll
    for (int s = 0; s < 4; ++s) {
        if (base + s < N) part[base + s] = p;
        p += v[s];
    }
}

__global__ __launch_bounds__(256) void scan2_kernel(int* __restrict__ bsum, int nb)
{
    __shared__ int lds[256];
    int t = threadIdx.x;
    int v = (t < nb) ? bsum[t] : 0;
    lds[t] = v;
    __syncthreads();
    for (int off = 1; off < 256; off <<= 1) {
        int xv = (t >= off) ? lds[t - off] : 0;
        __syncthreads();
        lds[t] += xv;
        __syncthreads();
    }
    if (t < nb) bsum[t] = lds[t] - v;
}

__global__ __launch_bounds__(256) void scan3_kernel(
    int* __restrict__ part, const int* __restrict__ bsum,
    int* __restrict__ cursor, int N)
{
    int i = blockIdx.x * 256 + threadIdx.x;
    if (i >= N) return;
    int s = part[i] + bsum[i >> 10];
    part[i] = s;
    cursor[i] = s;
}

__global__ __launch_bounds__(256) void scatter_kernel(
    const int* __restrict__ row, const int* __restrict__ col,
    const float* __restrict__ ew, int* __restrict__ cursor,
    int* __restrict__ rowS, int* __restrict__ colS,
    float* __restrict__ ewS, int E)
{
    int e = blockIdx.x * 256 + threadIdx.x;
    if (e >= E) return;
    int c = col[e];
    int p = atomicAdd(cursor + c, 1);
    rowS[p] = row[e];
    colS[p] = c;
    ewS[p] = ew[e];
}

// ----------------------------------------------------------------- edge ----
// lane = sorted-edge in [e0,e1); weights wave-uniform (SGPR). colS sorted ->
// x[colS] hits L1. Writes h*fw as bf16 (chunk-local index) + fw.
__global__ __launch_bounds__(256) void edge_kernel(
    const float* __restrict__ x,
    const int* __restrict__ rowS, const int* __restrict__ colS,
    const float* __restrict__ ewS,
    const float* __restrict__ W1, const float* __restrict__ b1,
    const float* __restrict__ aW1, const float* __restrict__ ab1,
    const float* __restrict__ aW2, const float* __restrict__ ab2,
    __hip_bfloat16* __restrict__ hfw, float* __restrict__ fwbuf,
    int e0, int e1)
{
    int e = e0 + blockIdx.x * 256 + threadIdx.x;
    if (e >= e1) return;
    const float4* xr = (const float4*)(x + (size_t)rowS[e] * H);
    const float4* xc = (const float4*)(x + (size_t)colS[e] * H);

    float fw;
    {
        float acca[H / 2];
#pragma unroll
        for (int j = 0; j < H / 2; ++j) acca[j] = 0.f;
#pragma unroll
        for (int half = 0; half < 2; ++half) {
            const float4* src = half ? xc : xr;
            const float* aW = aW1 + half * H * (H / 2);
            for (int i4 = 0; i4 < H / 4; ++i4) {
                float4 v = src[i4];
#pragma unroll
                for (int s = 0; s < 4; ++s) {
                    float cs = (s == 0) ? v.x : (s == 1) ? v.y : (s == 2) ? v.z : v.w;
                    const float* w = aW + (i4 * 4 + s) * (H / 2);
#pragma unroll
                    for (int j = 0; j < H / 2; ++j) acca[j] += cs * w[j];
                }
            }
        }
        float za = ab2[0];
#pragma unroll
        for (int k = 0; k < H / 2; ++k)
            za += fmaxf(acca[k] + ab1[k], 0.f) * aW2[k];
        fw = ewS[e] / (1.f + __expf(-za));
    }

    float accm[H];
#pragma unroll
    for (int j = 0; j < H; ++j) accm[j] = 0.f;
#pragma unroll
    for (int half = 0; half < 2; ++half) {
        const float4* src = half ? xc : xr;
        const float* Wh = W1 + half * H * H;
        for (int i4 = 0; i4 < H / 4; ++i4) {
            float4 v = src[i4];
#pragma unroll
            for (int s = 0; s < 4; ++s) {
                float cs = (s == 0) ? v.x : (s == 1) ? v.y : (s == 2) ? v.z : v.w;
                const float* w = Wh + (i4 * 4 + s) * H;
#pragma unroll
                for (int j = 0; j < H; ++j) accm[j] += cs * w[j];
            }
        }
    }

    int le = e - e0;
    uint4* out = (uint4*)(hfw + (size_t)le * H);
#pragma unroll
    for (int g = 0; g < H / 8; ++g) {
        union { unsigned short u[8]; uint4 v; } pk;
#pragma unroll
        for (int s = 0; s < 8; ++s) {
            float val = fmaxf(accm[8 * g + s] + b1[8 * g + s], 0.f) * fw;
            __hip_bfloat16 hb = __float2bfloat16(val);
            pk.u[s] = *reinterpret_cast<unsigned short*>(&hb);
        }
        out[g] = pk.v;
    }
    fwbuf[le] = fw;
}

// --------------------------------------------------------------- gather ----
// wave per node, lane per feature; node's segment clipped to chunk [e0,e1);
// accumulates += into agg/fwsum (zeroed per layer). No atomics, no chase.
__global__ __launch_bounds__(256) void gather_kernel(
    const __hip_bfloat16* __restrict__ hfw, const float* __restrict__ fwbuf,
    const int* __restrict__ startp, const int* __restrict__ deg,
    float* __restrict__ agg, float* __restrict__ fwsum,
    int N, int e0, int e1)
{
    int wid = (blockIdx.x * 256 + threadIdx.x) >> 6;
    int lane = threadIdx.x & 63;
    if (wid >= N) return;
    int s = startp[wid];
    int endv = s + deg[wid];
    int lo = s > e0 ? s : e0;
    int hi = endv < e1 ? endv : e1;
    if (lo >= hi) return;
    int d = hi - lo;
    int base = lo - e0;
    float acc = 0.f;
    const __hip_bfloat16* hp = hfw + (size_t)base * H + lane;
    for (int i = 0; i < d; ++i) acc += __bfloat162float(hp[(size_t)i * H]);
    float fwl = 0.f;
    for (int i = lane; i < d; i += 64) fwl += fwbuf[base + i];
#pragma unroll
    for (int off = 32; off > 0; off >>= 1) fwl += __shfl_down(fwl, off);
    agg[(size_t)wid * H + lane] += acc;
    if (lane == 0) fwsum[wid] += fwl;
}

// --------------------------------------------------------------- update ----
__global__ __launch_bounds__(256) void update_kernel(
    float* __restrict__ x, const float* __restrict__ agg,
    const float* __restrict__ fwsum,
    const float* __restrict__ mW2, const float* __restrict__ mb2,
    const float* __restrict__ W1, const float* __restrict__ b1,
    const float* __restrict__ W2, const float* __restrict__ b2, int N)
{
    int n = blockIdx.x * 256 + threadIdx.x;
    if (n >= N) return;
    float fws = fwsum[n];
    float inv = 1.f / fmaxf(fws, 1e-6f);

    float aggv[H];
#pragma unroll
    for (int j = 0; j < H; ++j) aggv[j] = fws * mb2[j];
    const float4* ga = (const float4*)(agg + (size_t)n * H);
    for (int i4 = 0; i4 < H / 4; ++i4) {
        float4 v = ga[i4];
#pragma unroll
        for (int s = 0; s < 4; ++s) {
            float cs = (s == 0) ? v.x : (s == 1) ? v.y : (s == 2) ? v.z : v.w;
            const float* w = mW2 + (i4 * 4 + s) * H;
#pragma unroll
            for (int j = 0; j < H; ++j) aggv[j] += cs * w[j];
        }
    }
#pragma unroll
    for (int j = 0; j < H; ++j) aggv[j] *= inv;

    float accu[H];
#pragma unroll
    for (int j = 0; j < H; ++j) accu[j] = 0.f;
    const float4* xa = (const float4*)(x + (size_t)n * H);
    for (int i4 = 0; i4 < H / 4; ++i4) {
        float4 v = xa[i4];
#pragma unroll
        for (int s = 0; s < 4; ++s) {
            float cs = (s == 0) ? v.x : (s == 1) ? v.y : (s == 2) ? v.z : v.w;
            const float* w = W1 + (i4 * 4 + s) * H;
#pragma unroll
            for (int j = 0; j < H; ++j) accu[j] += cs * w[j];
        }
    }
#pragma unroll
    for (int k = 0; k < H; ++k) {
        float cs = aggv[k];
        const float* w = W1 + (H + k) * H;
#pragma unroll
        for (int j = 0; j < H; ++j) accu[j] += cs * w[j];
    }

    float h[H];
#pragma unroll
    for (int k = 0; k < H; ++k) h[k] = fmaxf(accu[k] + b1[k], 0.f);
    float acc2[H];
#pragma unroll
    for (int j = 0; j < H; ++j) acc2[j] = b2[j];
#pragma unroll
    for (int k = 0; k < H; ++k) {
        float hk = h[k];
        const float* w = W2 + k * H;
#pragma unroll
        for (int j = 0; j < H; ++j) acc2[j] += hk * w[j];
    }

    float* xo = x + (size_t)n * H;
#pragma unroll
    for (int j = 0; j < H; ++j) xo[j] = fmaxf(acc2[j] + xo[j], 0.f);
}

// ----------------------------------------------------------------- head ----
__global__ __launch_bounds__(256) void max_kernel(
    const float* __restrict__ x, unsigned int* __restrict__ serp, int N)
{
    int j = threadIdx.x & (H - 1);
    int g = (blockIdx.x * 256 + threadIdx.x) >> 6;
    int stride = (gridDim.x * 256) >> 6;
    float m = 0.f;  // x >= 0 after relu
    for (int n = g; n < N; n += stride) m = fmaxf(m, x[(size_t)n * H + j]);
    atomicMax(serp + j, __float_as_uint(m));
}

__global__ void head_kernel(const unsigned int* __restrict__ serp,
                            const float* __restrict__ hW,
                            const float* __restrict__ hb,
                            float* __restrict__ out)
{
    int j = threadIdx.x;  // 64 threads = 1 wave
    float v = __uint_as_float(serp[j]) * hW[j];
#pragma unroll
    for (int off = 32; off > 0; off >>= 1) v += __shfl_down(v, off);
    if (j == 0) out[0] = v + hb[0];
}

// --------------------------------------------------------------- launch ----
extern "C" void kernel_launch(void* const* d_in, const int* in_sizes, int n_in,
                              void* d_out, int out_size, void* d_ws, size_t ws_size,
                              hipStream_t stream)
{
    const float* nf  = (const float*)d_in[0];
    const int*   ei  = (const int*)d_in[1];
    const float* ew  = (const float*)d_in[2];
    const float* eW  = (const float*)d_in[3];
    const float* eb  = (const float*)d_in[4];
    const float* mW1 = (const float*)d_in[5];
    const float* mb1 = (const float*)d_in[6];
    const float* mW2 = (const float*)d_in[7];
    const float* mb2 = (const float*)d_in[8];
    const float* aW1 = (const float*)d_in[9];
    const float* ab1 = (const float*)d_in[10];
    const float* aW2 = (const float*)d_in[11];
    const float* ab2 = (const float*)d_in[12];
    const float* uW1 = (const float*)d_in[13];
    const float* ub1 = (const float*)d_in[14];
    const float* uW2 = (const float*)d_in[15];
    const float* ub2 = (const float*)d_in[16];
    const float* hW  = (const float*)d_in[17];
    const float* hb  = (const float*)d_in[18];

    int N = in_sizes[0] / F;
    int E = in_sizes[2];
    const int* row = ei;
    const int* col = ei + E;

    size_t Nr = ((size_t)N + 3) & ~(size_t)3;   // 16B-aligned strides
    size_t Er = ((size_t)E + 3) & ~(size_t)3;

    // pick smallest chunk count k whose layout fits ws_size
    int k = 16;
    size_t ce = 0;
    const int kcand[5] = {1, 2, 4, 8, 16};
    for (int i = 0; i < 5; ++i) {
        int kk = kcand[i];
        size_t c = (((size_t)E + kk - 1) / kk + 3) & ~(size_t)3;
        size_t elems = 2 * Nr * H    // x, agg
                     + Nr            // fwsum
                     + 64            // serp
                     + 3 * Nr        // deg, startp, cursor
                     + 256           // bsum
                     + 3 * Er        // rowS, colS, ewS
                     + c             // fwbuf
                     + c * H / 2;    // hfw (bf16)
        if (elems * 4 <= ws_size || i == 4) { k = kk; ce = c; break; }
    }
    int chunkE = (int)ce;

    float* x      = (float*)d_ws;                    // Nr*H
    float* agg    = x + Nr * H;                      // Nr*H
    float* fwsum  = agg + Nr * H;                    // Nr (contiguous w/ agg)
    unsigned int* serp = (unsigned int*)(fwsum + Nr);// 64
    int*   deg    = (int*)(serp + 64);               // Nr
    int*   startp = deg + Nr;                        // Nr
    int*   cursor = startp + Nr;                     // Nr
    int*   bsum   = cursor + Nr;                     // 256
    int*   rowS   = bsum + 256;                      // Er
    int*   colS   = rowS + Er;                       // Er
    float* ewS    = (float*)(colS + Er);             // Er
    float* fwbuf  = ewS + Er;                        // ce
    __hip_bfloat16* hfw = (__hip_bfloat16*)(fwbuf + ce);  // ce*H bf16

    int nb_n = (N + 255) / 256;
    int nb_e = (E + 255) / 256;
    int nb_scan = (N + 1023) / 1024;  // <=256 (N<=262144)

    // ---- counting sort by destination (reused by both layers) ----
    hipMemsetAsync(deg, 0, (size_t)N * sizeof(int), stream);
    hist_kernel<<<nb_e, 256, 0, stream>>>(col, deg, E);
    scan1_kernel<<<nb_scan, 256, 0, stream>>>(deg, startp, bsum, N);
    scan2_kernel<<<1, 256, 0, stream>>>(bsum, nb_scan);
    scan3_kernel<<<nb_n, 256, 0, stream>>>(startp, bsum, cursor, N);
    scatter_kernel<<<nb_e, 256, 0, stream>>>(row, col, ew, cursor,
                                             rowS, colS, ewS, E);

    embed_kernel<<<nb_n, 256, 0, stream>>>(nf, eW, eb, x, N);

    for (int l = 0; l < 2; ++l) {
        hipMemsetAsync(agg, 0, (Nr * H + Nr) * sizeof(float), stream);
        for (int c = 0; c < k; ++c) {
            int e0 = c * chunkE;
            if (e0 >= E) break;
            int e1 = (e0 + chunkE < E) ? e0 + chunkE : E;
            int nb_c = (e1 - e0 + 255) / 256;
            edge_kernel<<<nb_c, 256, 0, stream>>>(
                x, rowS, colS, ewS,
                mW1 + (size_t)l * 2 * H * H, mb1 + (size_t)l * H,
                aW1 + (size_t)l * 2 * H * (H / 2), ab1 + (size_t)l * (H / 2),
                aW2 + (size_t)l * (H / 2),   ab2 + (size_t)l,
                hfw, fwbuf, e0, e1);
            gather_kernel<<<(N + 3) / 4, 256, 0, stream>>>(
                hfw, fwbuf, startp, deg, agg, fwsum, N, e0, e1);
        }
        update_kernel<<<nb_n, 256, 0, stream>>>(
            x, agg, fwsum,
            mW2 + (size_t)l * H * H,     mb2 + (size_t)l * H,
            uW1 + (size_t)l * 2 * H * H, ub1 + (size_t)l * H,
            uW2 + (size_t)l * H * H,     ub2 + (size_t)l * H, N);
    }

    hipMemsetAsync(serp, 0, 64 * sizeof(unsigned int), stream);
    max_kernel<<<256, 256, 0, stream>>>(x, serp, N);
    head_kernel<<<1, 64, 0, stream>>>(serp, hW, hb, (float*)d_out);
}